// Round 1
// baseline (84.600 us; speedup 1.0000x reference)
//
#include <hip/hip_runtime.h>

// PSA "collect": out[n, i*W+j, h, w] = x[n, (i-h+H-1)*(2W-1) + (j-w+W-1), h, w]
// N=2, H=W=64, C=127*127=16129. Pure permutation-gather (bijective on valid set).
//
// Strategy: block per (n, h, i). dr = i-h+63 fixed; need all cc in [0,127) at
// spatial row h -> 127 contiguous 64-float rows. Stage (partial, predicated)
// rows in LDS, then diagonal-read tile[(j-w+63)][w] and write coalesced
// 256B output rows.

#define H_ 64
#define W_ 64
#define C_ 16129   // 127*127
#define RW_ 127    // 2*W-1
#define TS_ 68     // LDS row stride in floats (pad 64 -> 68: odd bank walk)

__global__ __launch_bounds__(256) void collect_kernel(const float* __restrict__ x,
                                                      float* __restrict__ out) {
    __shared__ float tile[RW_ * TS_];   // 127*68*4 = 34544 B

    const int b = blockIdx.x;
    const int n = b >> 12;          // b / 4096
    const int h = (b >> 6) & 63;
    const int i = b & 63;
    const int dr = i - h + 63;      // channel row, always in [0,126]

    const int t = threadIdx.x;

    // ---- load phase: 127 rows x 16 float4 slots = 2032 slots, predicated ----
    // src + cc*(H_*W_) + w  is x[n][dr*127+cc][h][w]
    const float* __restrict__ src =
        x + (((size_t)n * C_ + (size_t)dr * RW_) * H_ + h) * W_;

    #pragma unroll
    for (int k = 0; k < 8; ++k) {
        const int idx = t + k * 256;
        if (idx < RW_ * 16) {
            const int cc = idx >> 4;
            const int s4 = idx & 15;
            // used w range for this row: j = cc + w - 63 in [0,64)
            const int w0 = max(0, 63 - cc);
            const int w1 = min(63, 126 - cc);
            if (s4 >= (w0 >> 2) && s4 <= (w1 >> 2)) {
                const float4 v =
                    *reinterpret_cast<const float4*>(src + (size_t)cc * (H_ * W_) + s4 * 4);
                *reinterpret_cast<float4*>(&tile[cc * TS_ + s4 * 4]) = v;
            }
        }
    }
    __syncthreads();

    // ---- write phase: thread (j0 = t>>6, w = t&63); j = j0 + 4k ----
    const int w  = t & 63;
    const int j0 = t >> 6;
    float* __restrict__ dst =
        out + (((size_t)n * (H_ * W_) + (size_t)i * W_) * H_ + h) * W_ + w;

    #pragma unroll
    for (int k = 0; k < 16; ++k) {
        const int j  = j0 + 4 * k;
        const int cc = j - w + 63;          // in [0,127)
        dst[(size_t)j * (H_ * W_)] = tile[cc * TS_ + w];
    }
}

extern "C" void kernel_launch(void* const* d_in, const int* in_sizes, int n_in,
                              void* d_out, int out_size, void* d_ws, size_t ws_size,
                              hipStream_t stream) {
    const float* x = (const float*)d_in[0];
    float* out = (float*)d_out;
    // grid = N * H * H(=i) = 2*64*64 = 8192 blocks
    collect_kernel<<<dim3(8192), dim3(256), 0, stream>>>(x, out);
}

// Round 2
// 76.480 us; speedup vs baseline: 1.1062x; 1.1062x over previous
//
#include <hip/hip_runtime.h>

// PSA "collect": out[n, i*W+j, h, w] = x[n, (i-h+63)*127 + (j-w+63), h, w]
// N=2, H=W=64. Pure permutation-gather (bijection on the valid set).
//
// Block per (n, h, i); dr = i-h+63 fixed. Diagonal LDS layout:
//   tile[j][w] = x[n][dr*127 + (j-w+63)][h][w]
// Load phase scatters predicated float4 row-loads into the diagonal tile
// (scalar ds_writes, latency-tolerant). Write phase is fully vectorized:
// ds_read_b128 + global_store_dwordx4, 256B/wave coalesced segments.
// LDS = 64*68*4 = 17.4 KB -> 8 blocks/CU (32 waves, 100% occupancy).

#define H_ 64
#define W_ 64
#define C_ 16129   // 127*127
#define RW_ 127    // 2*W-1
#define TS_ 68     // tile row stride in floats (68*4=272 B, 16B-aligned rows)

__global__ __launch_bounds__(256, 8) void collect_kernel(const float* __restrict__ x,
                                                         float* __restrict__ out) {
    __shared__ float tile[H_ * TS_];   // 17408 B, diagonal layout tile[j][w]

    const int b = blockIdx.x;
    const int n = b >> 12;          // b / 4096
    const int h = (b >> 6) & 63;
    const int i = b & 63;
    const int dr = i - h + 63;      // channel row, always in [0,126]

    const int t = threadIdx.x;

    // x[n][dr*127 + cc][h][w] = src[cc*4096 + w]
    const float* __restrict__ src =
        x + (((size_t)n * C_ + (size_t)dr * RW_) * H_ + h) * W_;

    // ---- load phase: 127 rows x 16 float4 slots, predicated to used span ----
    #pragma unroll
    for (int k = 0; k < 8; ++k) {
        const int idx = t + k * 256;
        if (idx < RW_ * 16) {
            const int cc = idx >> 4;
            const int s4 = idx & 15;
            // used w range for row cc: j = cc + w - 63 must be in [0,64)
            const int w0 = max(0, 63 - cc);
            const int w1 = min(63, 126 - cc);
            if (s4 >= (w0 >> 2) && s4 <= (w1 >> 2)) {
                const float4 v =
                    *reinterpret_cast<const float4*>(src + cc * (H_ * W_) + s4 * 4);
                const int jb = cc + s4 * 4 - 63;   // j for element e=0
                const float* vf = reinterpret_cast<const float*>(&v);
                #pragma unroll
                for (int e = 0; e < 4; ++e) {
                    const int j = jb + e;
                    if ((unsigned)j < (unsigned)H_) {
                        tile[j * TS_ + s4 * 4 + e] = vf[e];
                    }
                }
            }
        }
    }
    __syncthreads();

    // ---- write phase: vectorized. thread t -> (j0 = t>>4, w4 = t&15) ----
    const int w4 = t & 15;
    const int j0 = t >> 4;
    float* __restrict__ dstbase =
        out + (((size_t)n * (H_ * W_) + (size_t)i * W_) * H_ + h) * W_ + w4 * 4;

    #pragma unroll
    for (int k = 0; k < 4; ++k) {
        const int j = j0 + k * 16;
        *reinterpret_cast<float4*>(dstbase + (size_t)j * (H_ * W_)) =
            *reinterpret_cast<const float4*>(&tile[j * TS_ + w4 * 4]);
    }
}

extern "C" void kernel_launch(void* const* d_in, const int* in_sizes, int n_in,
                              void* d_out, int out_size, void* d_ws, size_t ws_size,
                              hipStream_t stream) {
    const float* x = (const float*)d_in[0];
    float* out = (float*)d_out;
    collect_kernel<<<dim3(8192), dim3(256), 0, stream>>>(x, out);
}

// Round 3
// 68.957 us; speedup vs baseline: 1.2268x; 1.1091x over previous
//
#include <hip/hip_runtime.h>

// PSA "collect": out[n, i*W+j, h, w] = x[n, (i-h+63)*127 + (j-w+63), h, w]
// N=2, H=W=64. Pure permutation-gather (bijection on the valid set).
//
// Block per (n, s, h) with i = (h+s) & 63  ->  dr = i-h+63 in {s+63, s-1}.
// For fixed s, consecutive h-blocks read ADJACENT 256B chunks of the SAME
// channel rows (input layout [c][h][w]) -> co-resident blocks sweep
// contiguous multi-MB read regions (DRAM page locality) instead of random
// 256B granules. Diagonal LDS tile as before:
//   tile[j][w] = x[n][dr*127 + (j-w+63)][h][w]
// Write phase: ds_read_b128 + global_store_dwordx4, 256B/wave segments.
// LDS = 64*68*4 = 17.4 KB -> 8 blocks/CU.

#define H_ 64
#define W_ 64
#define C_ 16129   // 127*127
#define RW_ 127    // 2*W-1
#define TS_ 68     // tile row stride in floats

__global__ __launch_bounds__(256, 8) void collect_kernel(const float* __restrict__ x,
                                                         float* __restrict__ out) {
    __shared__ float tile[H_ * TS_];   // diagonal layout tile[j][w]

    const int b = blockIdx.x;
    const int n = b >> 12;          // b / 4096
    const int s = (b >> 6) & 63;    // slow: diagonal class
    const int h = b & 63;           // fast: spatial row (contiguous reads)
    const int i = (h + s) & 63;
    const int dr = i - h + 63;      // in {s+63, s-1}, always [0,126]

    const int t = threadIdx.x;

    // x[n][dr*127 + cc][h][w] = src[cc*4096 + w]
    const float* __restrict__ src =
        x + (((size_t)n * C_ + (size_t)dr * RW_) * H_ + h) * W_;

    // ---- load phase: 127 rows x 16 float4 slots, predicated to used span ----
    #pragma unroll
    for (int k = 0; k < 8; ++k) {
        const int idx = t + k * 256;
        if (idx < RW_ * 16) {
            const int cc = idx >> 4;
            const int s4 = idx & 15;
            // used w range for row cc: j = cc + w - 63 must be in [0,64)
            const int w0 = max(0, 63 - cc);
            const int w1 = min(63, 126 - cc);
            if (s4 >= (w0 >> 2) && s4 <= (w1 >> 2)) {
                const float4 v =
                    *reinterpret_cast<const float4*>(src + cc * (H_ * W_) + s4 * 4);
                const int jb = cc + s4 * 4 - 63;   // j for element e=0
                const float* vf = reinterpret_cast<const float*>(&v);
                #pragma unroll
                for (int e = 0; e < 4; ++e) {
                    const int j = jb + e;
                    if ((unsigned)j < (unsigned)H_) {
                        tile[j * TS_ + s4 * 4 + e] = vf[e];
                    }
                }
            }
        }
    }
    __syncthreads();

    // ---- write phase: vectorized. thread t -> (j0 = t>>4, w4 = t&15) ----
    const int w4 = t & 15;
    const int j0 = t >> 4;
    float* __restrict__ dstbase =
        out + (((size_t)n * (H_ * W_) + (size_t)i * W_) * H_ + h) * W_ + w4 * 4;

    #pragma unroll
    for (int k = 0; k < 4; ++k) {
        const int j = j0 + k * 16;
        *reinterpret_cast<float4*>(dstbase + (size_t)j * (H_ * W_)) =
            *reinterpret_cast<const float4*>(&tile[j * TS_ + w4 * 4]);
    }
}

extern "C" void kernel_launch(void* const* d_in, const int* in_sizes, int n_in,
                              void* d_out, int out_size, void* d_ws, size_t ws_size,
                              hipStream_t stream) {
    const float* x = (const float*)d_in[0];
    float* out = (float*)d_out;
    collect_kernel<<<dim3(8192), dim3(256), 0, stream>>>(x, out);
}